// Round 2
// baseline (710.791 us; speedup 1.0000x reference)
//
#include <hip/hip_runtime.h>

// EfficientSelfAttention (PVT-style), B=8, N=16384 (128x128), C=64, 1 head, SR=8.
// Round 1 (resubmit after GPU acquisition timeout): fully-fp32 fused implementation
// (correctness anchor for later MFMA rounds).
//
// ws layout (floats):
//   wperm2   [4096][64]  : permuted conv weights, k=(kh*512+kw*64+cin) major -> 262144
//   conv_out [2048][64]  : conv + bias accumulator                          -> 131072
//   kT       [8][64][256]: K transposed per batch (ch-major)                -> 131072
//   vbuf     [8][256][64]: V                                                -> 131072
// total 655360 floats = 2.56 MB

#define ATT_SCALE 0.125f

__device__ __forceinline__ float f4get(const float4& v, int u) {
    return ((const float*)&v)[u];
}

// ---------------- kernel 0: permute conv weights + init conv_out with bias ----
__global__ __launch_bounds__(256) void prep_kernel(
    const float* __restrict__ sr_w, const float* __restrict__ sr_b,
    float* __restrict__ wperm2, float* __restrict__ conv_out)
{
    int tid = blockIdx.x * 256 + threadIdx.x;   // 0 .. 262143
    {
        int k = tid >> 6, co = tid & 63;
        int kh = k >> 9, kw = (k >> 6) & 7, cin = k & 63;
        wperm2[tid] = sr_w[co * 4096 + cin * 64 + kh * 8 + kw];
    }
    if (tid < 2048 * 64) conv_out[tid] = sr_b[tid & 63];
}

// ---------------- kernel 1: strided 8x8 conv as GEMM (k-split x4, atomicAdd) --
// grid = 128 pos-tiles (b,oh) x 4 k-chunks; 256 threads; thread tile 2pos x 2co
__global__ __launch_bounds__(256) void conv_kernel(
    const float* __restrict__ x, const float* __restrict__ wperm2,
    float* __restrict__ conv_out)
{
    int pt = blockIdx.x >> 2;
    int kc = blockIdx.x & 3;          // k range [kc*1024, kc*1024+1024)
    int b  = pt >> 4;
    int oh = pt & 15;

    __shared__ float ps[16 * 132];    // [pos(=ow)][128 + pad4]
    __shared__ float ws[128 * 64];    // [kk][co]

    int t  = threadIdx.x;
    int pg = t >> 5;                  // 0..7
    int cg = t & 31;                  // 0..31
    int p0 = pg * 2;
    int c0 = cg * 2;

    float acc[2][2] = {{0.f, 0.f}, {0.f, 0.f}};

    for (int ch = 0; ch < 8; ++ch) {
        int kb  = kc * 1024 + ch * 128;
        int kh  = kb >> 9;
        int rem = kb & 511;           // = kw0*64, cin-contiguous
        // stage patch rows: 16 pos x 128 k (contiguous in x per pos)
        {
            int p   = t >> 4;         // 0..15  (= ow)
            int off = (t & 15) * 8;   // 0..120
            const float* src = x + (size_t)(b * 16384 + (oh * 8 + kh) * 128 + p * 8) * 64 + rem + off;
            float4 v0 = *(const float4*)(src);
            float4 v1 = *(const float4*)(src + 4);
            *(float4*)&ps[p * 132 + off]     = v0;
            *(float4*)&ps[p * 132 + off + 4] = v1;
        }
        // stage weights: 128 x 64 contiguous
        {
            const float* srcw = wperm2 + (size_t)kb * 64 + t * 32;
            float* dstw = ws + t * 32;
            #pragma unroll
            for (int i = 0; i < 32; i += 4)
                *(float4*)(dstw + i) = *(const float4*)(srcw + i);
        }
        __syncthreads();

        for (int kk = 0; kk < 128; kk += 4) {
            float4 a0 = *(const float4*)&ps[(p0    ) * 132 + kk];
            float4 a1 = *(const float4*)&ps[(p0 + 1) * 132 + kk];
            #pragma unroll
            for (int u = 0; u < 4; ++u) {
                float2 w2 = *(const float2*)&ws[(kk + u) * 64 + c0];
                float a0u = f4get(a0, u), a1u = f4get(a1, u);
                acc[0][0] += a0u * w2.x; acc[0][1] += a0u * w2.y;
                acc[1][0] += a1u * w2.x; acc[1][1] += a1u * w2.y;
            }
        }
        __syncthreads();
    }
    int gpos = b * 256 + oh * 16;
    #pragma unroll
    for (int i = 0; i < 2; ++i)
        #pragma unroll
        for (int j = 0; j < 2; ++j)
            atomicAdd(&conv_out[(gpos + p0 + i) * 64 + c0 + j], acc[i][j]);
}

// ---------------- kernel 2: LayerNorm + kv projection, writes kT and v -------
// grid = 2048 blocks (one per (b, m)), 64 threads
__global__ __launch_bounds__(64) void lnkv_kernel(
    const float* __restrict__ conv_out,
    const float* __restrict__ ln_g, const float* __restrict__ ln_b,
    const float* __restrict__ kv_w, const float* __restrict__ kv_b,
    float* __restrict__ kT, float* __restrict__ vbuf)
{
    int g = blockIdx.x;
    int b = g >> 8, m = g & 255;
    int c = threadIdx.x;
    float val = conv_out[g * 64 + c];
    float s = val, s2 = val * val;
    #pragma unroll
    for (int o = 32; o >= 1; o >>= 1) {
        s  += __shfl_xor(s, o, 64);
        s2 += __shfl_xor(s2, o, 64);
    }
    float mean = s * (1.f / 64.f);
    float var  = s2 * (1.f / 64.f) - mean * mean;
    float y = (val - mean) * rsqrtf(var + 1e-5f) * ln_g[c] + ln_b[c];

    __shared__ float ys[64];
    ys[c] = y;
    __syncthreads();

    #pragma unroll
    for (int h = 0; h < 2; ++h) {
        int oc = c + h * 64;
        float acc = kv_b[oc];
        const float* wr = kv_w + oc * 64;
        #pragma unroll
        for (int j = 0; j < 64; j += 4) {
            float4 w4 = *(const float4*)(wr + j);
            acc += ys[j] * w4.x + ys[j + 1] * w4.y + ys[j + 2] * w4.z + ys[j + 3] * w4.w;
        }
        if (h == 0) kT[(b * 64 + c) * 256 + m] = acc;       // K^T: [b][ch][m]
        else        vbuf[(b * 256 + m) * 64 + c] = acc;     // V:   [b][m][ch]
    }
}

// ---------------- kernel 3: fused q-proj + QK^T + softmax + PV + out-proj ----
// grid = 8 x 512 blocks (32 query rows each), 256 threads
__global__ __launch_bounds__(256) void attn_kernel(
    const float* __restrict__ x,
    const float* __restrict__ q_w, const float* __restrict__ q_b,
    const float* __restrict__ kT, const float* __restrict__ vbuf,
    const float* __restrict__ proj_w, const float* __restrict__ proj_b,
    float* __restrict__ out)
{
    int bid = blockIdx.x;
    int b   = bid >> 9;
    int rt  = bid & 511;
    int gr0 = rt * 32;
    const size_t xbase = (size_t)(b * 16384 + gr0) * 64;

    __shared__ float xs[32 * 68];     // input rows; reused for PV output
    __shared__ float qb[32 * 68];     // scaled q rows
    __shared__ float at[32 * 264];    // logits -> probs

    int t = threadIdx.x;

    // P0: stage 32x64 input rows
    {
        int r = t >> 3, c = (t & 7) * 8;
        float4 v0 = *(const float4*)(x + xbase + r * 64 + c);
        float4 v1 = *(const float4*)(x + xbase + r * 64 + c + 4);
        *(float4*)&xs[r * 68 + c]     = v0;
        *(float4*)&xs[r * 68 + c + 4] = v1;
    }
    __syncthreads();

    int rg = t >> 4, cg = t & 15;
    int r0 = rg * 2, c0 = cg * 4;

    // P1: q = (x @ q_w.T + q_b) * SCALE
    {
        float acc[2][4];
        #pragma unroll
        for (int i = 0; i < 2; ++i)
            #pragma unroll
            for (int j = 0; j < 4; ++j) acc[i][j] = q_b[c0 + j];
        for (int k = 0; k < 64; k += 4) {
            float4 a0 = *(const float4*)&xs[(r0    ) * 68 + k];
            float4 a1 = *(const float4*)&xs[(r0 + 1) * 68 + k];
            #pragma unroll
            for (int j = 0; j < 4; ++j) {
                float4 w = *(const float4*)(q_w + (c0 + j) * 64 + k);
                acc[0][j] += a0.x * w.x + a0.y * w.y + a0.z * w.z + a0.w * w.w;
                acc[1][j] += a1.x * w.x + a1.y * w.y + a1.z * w.z + a1.w * w.w;
            }
        }
        *(float4*)&qb[(r0    ) * 68 + c0] = make_float4(acc[0][0] * ATT_SCALE, acc[0][1] * ATT_SCALE, acc[0][2] * ATT_SCALE, acc[0][3] * ATT_SCALE);
        *(float4*)&qb[(r0 + 1) * 68 + c0] = make_float4(acc[1][0] * ATT_SCALE, acc[1][1] * ATT_SCALE, acc[1][2] * ATT_SCALE, acc[1][3] * ATT_SCALE);
    }
    __syncthreads();

    // P2: logits[32][256] = q @ k^T (2 rows x 16 cols per thread)
    {
        int m0 = cg * 16;
        float4 acc[2][4];
        #pragma unroll
        for (int i = 0; i < 2; ++i)
            #pragma unroll
            for (int u = 0; u < 4; ++u) acc[i][u] = make_float4(0.f, 0.f, 0.f, 0.f);
        for (int k = 0; k < 64; ++k) {
            float q0 = qb[(r0    ) * 68 + k];
            float q1 = qb[(r0 + 1) * 68 + k];
            const float* kr = kT + ((size_t)(b * 64 + k) << 8) + m0;
            #pragma unroll
            for (int u = 0; u < 4; ++u) {
                float4 kv = *(const float4*)(kr + u * 4);
                acc[0][u].x += q0 * kv.x; acc[0][u].y += q0 * kv.y;
                acc[0][u].z += q0 * kv.z; acc[0][u].w += q0 * kv.w;
                acc[1][u].x += q1 * kv.x; acc[1][u].y += q1 * kv.y;
                acc[1][u].z += q1 * kv.z; acc[1][u].w += q1 * kv.w;
            }
        }
        #pragma unroll
        for (int i = 0; i < 2; ++i)
            #pragma unroll
            for (int u = 0; u < 4; ++u)
                *(float4*)&at[(r0 + i) * 264 + m0 + u * 4] = acc[i][u];
    }
    __syncthreads();

    // P3: softmax over 256 per row (8 lanes per row, stride-32 banks conflict-free)
    {
        int r = t >> 3, sub = t & 7;
        float f[32];
        #pragma unroll
        for (int u = 0; u < 8; ++u) {
            float4 v = *(const float4*)&at[r * 264 + sub * 4 + u * 32];
            f[u * 4 + 0] = v.x; f[u * 4 + 1] = v.y; f[u * 4 + 2] = v.z; f[u * 4 + 3] = v.w;
        }
        float mx = f[0];
        #pragma unroll
        for (int i = 1; i < 32; ++i) mx = fmaxf(mx, f[i]);
        #pragma unroll
        for (int o = 1; o <= 4; o <<= 1) mx = fmaxf(mx, __shfl_xor(mx, o, 64));
        float sum = 0.f;
        #pragma unroll
        for (int i = 0; i < 32; ++i) { f[i] = __expf(f[i] - mx); sum += f[i]; }
        #pragma unroll
        for (int o = 1; o <= 4; o <<= 1) sum += __shfl_xor(sum, o, 64);
        float inv = 1.f / sum;
        #pragma unroll
        for (int u = 0; u < 8; ++u) {
            *(float4*)&at[r * 264 + sub * 4 + u * 32] =
                make_float4(f[u * 4 + 0] * inv, f[u * 4 + 1] * inv, f[u * 4 + 2] * inv, f[u * 4 + 3] * inv);
        }
    }
    __syncthreads();

    // P4: out = probs @ v  (2 rows x 4 ch per thread), into xs (dead)
    {
        float acc[2][4] = {{0.f, 0.f, 0.f, 0.f}, {0.f, 0.f, 0.f, 0.f}};
        for (int m = 0; m < 256; m += 4) {
            float4 p0v = *(const float4*)&at[(r0    ) * 264 + m];
            float4 p1v = *(const float4*)&at[(r0 + 1) * 264 + m];
            #pragma unroll
            for (int u = 0; u < 4; ++u) {
                float4 vv = *(const float4*)(vbuf + (size_t)((b << 8) + m + u) * 64 + c0);
                float pu0 = f4get(p0v, u), pu1 = f4get(p1v, u);
                acc[0][0] += pu0 * vv.x; acc[0][1] += pu0 * vv.y;
                acc[0][2] += pu0 * vv.z; acc[0][3] += pu0 * vv.w;
                acc[1][0] += pu1 * vv.x; acc[1][1] += pu1 * vv.y;
                acc[1][2] += pu1 * vv.z; acc[1][3] += pu1 * vv.w;
            }
        }
        *(float4*)&xs[(r0    ) * 68 + c0] = make_float4(acc[0][0], acc[0][1], acc[0][2], acc[0][3]);
        *(float4*)&xs[(r0 + 1) * 68 + c0] = make_float4(acc[1][0], acc[1][1], acc[1][2], acc[1][3]);
    }
    __syncthreads();

    // P5: final = out @ proj_w.T + proj_b
    {
        float acc[2][4];
        #pragma unroll
        for (int i = 0; i < 2; ++i)
            #pragma unroll
            for (int j = 0; j < 4; ++j) acc[i][j] = proj_b[c0 + j];
        for (int k = 0; k < 64; k += 4) {
            float4 a0 = *(const float4*)&xs[(r0    ) * 68 + k];
            float4 a1 = *(const float4*)&xs[(r0 + 1) * 68 + k];
            #pragma unroll
            for (int j = 0; j < 4; ++j) {
                float4 w = *(const float4*)(proj_w + (c0 + j) * 64 + k);
                acc[0][j] += a0.x * w.x + a0.y * w.y + a0.z * w.z + a0.w * w.w;
                acc[1][j] += a1.x * w.x + a1.y * w.y + a1.z * w.z + a1.w * w.w;
            }
        }
        *(float4*)(out + (size_t)(b * 16384 + gr0 + r0    ) * 64 + c0) = make_float4(acc[0][0], acc[0][1], acc[0][2], acc[0][3]);
        *(float4*)(out + (size_t)(b * 16384 + gr0 + r0 + 1) * 64 + c0) = make_float4(acc[1][0], acc[1][1], acc[1][2], acc[1][3]);
    }
}

extern "C" void kernel_launch(void* const* d_in, const int* in_sizes, int n_in,
                              void* d_out, int out_size, void* d_ws, size_t ws_size,
                              hipStream_t stream)
{
    const float* x      = (const float*)d_in[0];
    const float* sr_w   = (const float*)d_in[1];
    const float* sr_b   = (const float*)d_in[2];
    const float* ln_g   = (const float*)d_in[3];
    const float* ln_b   = (const float*)d_in[4];
    const float* q_w    = (const float*)d_in[5];
    const float* q_b    = (const float*)d_in[6];
    const float* kv_w   = (const float*)d_in[7];
    const float* kv_b   = (const float*)d_in[8];
    const float* proj_w = (const float*)d_in[9];
    const float* proj_b = (const float*)d_in[10];
    float* out = (float*)d_out;

    float* ws       = (float*)d_ws;           // needs 2.56 MB
    float* wperm2   = ws;                     // 262144 floats
    float* conv_out = ws + 262144;            // 131072
    float* kT       = ws + 262144 + 131072;   // 131072
    float* vbuf     = ws + 262144 + 262144;   // 131072

    hipLaunchKernelGGL(prep_kernel, dim3(1024), dim3(256), 0, stream, sr_w, sr_b, wperm2, conv_out);
    hipLaunchKernelGGL(conv_kernel, dim3(512),  dim3(256), 0, stream, x, wperm2, conv_out);
    hipLaunchKernelGGL(lnkv_kernel, dim3(2048), dim3(64),  0, stream, conv_out, ln_g, ln_b, kv_w, kv_b, kT, vbuf);
    hipLaunchKernelGGL(attn_kernel, dim3(4096), dim3(256), 0, stream, x, q_w, q_b, kT, vbuf, proj_w, proj_b, out);
}

// Round 4
// 157.246 us; speedup vs baseline: 4.5202x; 4.5202x over previous
//
#include <hip/hip_runtime.h>

// EfficientSelfAttention (PVT-style), B=8, N=16384 (128x128), C=64, 1 head, SR=8.
// Round 2 (resubmit after container failure): all GEMM phases on bf16 MFMA
// (16x16x32), register-chained attention.
//
// Fragment conventions used (gfx950 mfma_f32_16x16x32_bf16):
//   A-slot (lane l, elem i): A[m = l&15][k = kappa(l>>4, i)]
//   B-slot (lane l, elem i): B[k = kappa(l>>4, i)][n = l&15]
//   D (lane l, reg r):       D[m = (l>>4)*4 + r][n = l&15]   (guide-verified)
// kappa unknown but identical for A and B -> loading both with any consistent
// bijection mu(g,i) of the k-range contracts correctly (mu-trick). Chaining:
// D-ownership (tau,r per lane) feeds the next MFMA's B-operand with
// mu(g,i,s) = 16*(2s + (i>>2)) + 4g + (i&3), which is lane-local.
//
// ws layout (bytes):
//   wbp      512KB  conv weights bf16, permuted for coalesced A-frag loads
//   conv_out 512KB  f32 conv accumulator (bias-init by prep, atomics by conv)
//   kbuf     256KB  K bf16 [b][256][64]
//   vp       256KB  V bf16 permuted [b][ks][g][ch][i]
//   qwb      8KB    q_w * scale, bf16
//   pwph/l   8+8KB  proj_w hi/lo split bf16, permuted
//   qb_s     256B   q_b * scale, f32

typedef __attribute__((ext_vector_type(8))) short bf16x8;
typedef __attribute__((ext_vector_type(4))) float f32x4;

__device__ __forceinline__ unsigned short f2bf(float f) {
    union { float f; unsigned int u; } a; a.f = f;
    unsigned int r = a.u + 0x7FFFu + ((a.u >> 16) & 1u);
    return (unsigned short)(r >> 16);
}
__device__ __forceinline__ float bf2f(unsigned short h) {
    union { unsigned int u; float f; } a; a.u = ((unsigned int)h) << 16;
    return a.f;
}
union U8 { uint4 u; bf16x8 v; };
__device__ __forceinline__ bf16x8 pack8(float e0,float e1,float e2,float e3,
                                        float e4,float e5,float e6,float e7){
    U8 r;
    r.u.x = (unsigned)f2bf(e0) | ((unsigned)f2bf(e1)<<16);
    r.u.y = (unsigned)f2bf(e2) | ((unsigned)f2bf(e3)<<16);
    r.u.z = (unsigned)f2bf(e4) | ((unsigned)f2bf(e5)<<16);
    r.u.w = (unsigned)f2bf(e6) | ((unsigned)f2bf(e7)<<16);
    return r.v;
}
__device__ __forceinline__ bf16x8 ldg8(const unsigned short* p){
    U8 r; r.u = *(const uint4*)p; return r.v;
}

// ---------------- kernel 0: weight permutes + conv_out bias init -------------
__global__ __launch_bounds__(256) void prep_kernel(
    const float* __restrict__ sr_w, const float* __restrict__ sr_b,
    const float* __restrict__ q_w, const float* __restrict__ q_b,
    const float* __restrict__ proj_w,
    unsigned short* __restrict__ wbp, float* __restrict__ conv_out,
    unsigned short* __restrict__ qwb, unsigned short* __restrict__ pwph,
    unsigned short* __restrict__ pwpl, float* __restrict__ qb_s)
{
    int tid = blockIdx.x * 256 + threadIdx.x;   // 0..262143
    {   // wbp[((((w*4+kc)*32+ks)*4+g)*16+n)*8+i] = bf16(W[16w+n][kc*1024+ks*32+8g+i])
        int i = tid & 7, n = (tid>>3)&15, g = (tid>>7)&3, ks = (tid>>9)&31,
            kc = (tid>>14)&3, w = tid>>16;
        int co = 16*w + n;
        int k  = kc*1024 + ks*32 + 8*g + i;
        int kh = k >> 9, kw = (k>>6)&7, cin = k & 63;
        wbp[tid] = f2bf(sr_w[co*4096 + cin*64 + kh*8 + kw]);
    }
    if (tid < 131072) conv_out[tid] = sr_b[tid & 63];
    if (tid < 4096)   qwb[tid] = f2bf(q_w[tid] * 0.125f);
    if (tid < 4096) { // pwp[((co*2+s3)*4+g)*8+i] = pw[co][16*(2s3+(i>>2))+4g+(i&3)]
        int i = tid & 7, g = (tid>>3)&3, s3 = (tid>>5)&1, co = tid>>6;
        int ch = 32*s3 + 16*(i>>2) + 4*g + (i&3);
        float w = proj_w[co*64 + ch];
        unsigned short h = f2bf(w);
        pwph[tid] = h;
        pwpl[tid] = f2bf(w - bf2f(h));
    }
    if (tid < 64) qb_s[tid] = q_b[tid] * 0.125f;
}

// ---------------- kernel 1: 8x8/8 conv as bf16 MFMA GEMM (k-split, atomics) --
// grid: b(8) x oh(16) x kc(4) = 512 blocks, 256 threads (4 waves, 1 co-tile each)
__global__ __launch_bounds__(256) void conv_kernel(
    const float* __restrict__ x, const unsigned short* __restrict__ wbp,
    float* __restrict__ conv_out)
{
    __shared__ char xsm[32768];   // 2 rows x 128 w x 64 cin bf16, XOR-swizzled by ow
    int bid = blockIdx.x;
    int kc = bid & 3, oh = (bid>>2) & 15, b = bid >> 6;
    int t = threadIdx.x;

    const float* slab = x + ((size_t)(b*128 + oh*8 + kc*2)) * 128 * 64;
    #pragma unroll
    for (int c2 = 0; c2 < 8; ++c2) {
        int eo = (c2*256 + t) * 8;
        float4 v0 = *(const float4*)(slab + eo);
        float4 v1 = *(const float4*)(slab + eo + 4);
        int byte = eo * 2;
        int dst = byte ^ (((byte >> 10) & 7) << 4);   // swizzle by ow row
        U8 tmp; tmp.v = pack8(v0.x,v0.y,v0.z,v0.w,v1.x,v1.y,v1.z,v1.w);
        *(uint4*)(xsm + dst) = tmp.u;
    }
    __syncthreads();

    int w = t >> 6, lane = t & 63, g = lane >> 4, n = lane & 15;
    f32x4 acc = {0.f, 0.f, 0.f, 0.f};
    const unsigned short* wslice = wbp + (size_t)((w*4 + kc) * 32) * 512; // *4*16*8
    int swz = (n & 7) << 4;
    #pragma unroll
    for (int ks = 0; ks < 32; ++ks) {
        bf16x8 A = ldg8(wslice + ((ks*4 + g)*16 + n) * 8);
        int byte = (ks >> 4) * 16384 + n * 1024 + ((ks & 15) * 32 + 8*g) * 2;
        U8 Bx; Bx.u = *(const uint4*)(xsm + (byte ^ swz));
        acc = __builtin_amdgcn_mfma_f32_16x16x32_bf16(A, Bx.v, acc, 0, 0, 0);
    }
    int pos = b*256 + oh*16 + n;
    int co  = 16*w + 4*g;
    #pragma unroll
    for (int r = 0; r < 4; ++r)
        atomicAdd(&conv_out[pos*64 + co + r], acc[r]);
}

// ---------------- kernel 2: LayerNorm + kv proj -> kbuf bf16, vp bf16 --------
__global__ __launch_bounds__(64) void lnkv_kernel(
    const float* __restrict__ conv_out,
    const float* __restrict__ ln_g, const float* __restrict__ ln_b,
    const float* __restrict__ kv_w, const float* __restrict__ kv_b,
    unsigned short* __restrict__ kbuf, unsigned short* __restrict__ vp)
{
    int gblk = blockIdx.x;            // b*256 + m
    int b = gblk >> 8, m = gblk & 255;
    int c = threadIdx.x;
    float val = conv_out[gblk*64 + c];
    float s = val, s2 = val*val;
    #pragma unroll
    for (int o = 32; o >= 1; o >>= 1) {
        s  += __shfl_xor(s,  o, 64);
        s2 += __shfl_xor(s2, o, 64);
    }
    float mean = s * (1.f/64.f);
    float var  = s2 * (1.f/64.f) - mean*mean;
    float y = (val - mean) * rsqrtf(var + 1e-5f) * ln_g[c] + ln_b[c];
    __shared__ float ys[64];
    ys[c] = y;
    __syncthreads();
    #pragma unroll
    for (int h = 0; h < 2; ++h) {
        int oc = c + h*64;
        float acc = kv_b[oc];
        const float* wr = kv_w + oc*64;
        #pragma unroll
        for (int j = 0; j < 64; j += 4) {
            float4 w4 = *(const float4*)(wr + j);
            acc += ys[j]*w4.x + ys[j+1]*w4.y + ys[j+2]*w4.z + ys[j+3]*w4.w;
        }
        if (h == 0) {
            kbuf[(b*256 + m)*64 + c] = f2bf(acc);
        } else {    // vp[b][((ks*4+g)*64+ch)*8 + (m&3) + 4*hi], m = 16(2ks+hi)+4g+r
            int ks = m >> 5, hi = (m >> 4) & 1, g2 = (m >> 2) & 3, r = m & 3;
            vp[(size_t)b*16384 + ((ks*4 + g2)*64 + c)*8 + r + 4*hi] = f2bf(acc);
        }
    }
}

// ---------------- kernel 3: fused q-proj/QK^T/softmax/PV/out-proj, all MFMA --
// grid: b(8) x 256 row-tiles = 2048 blocks; 4 waves x 16 q-rows = 64 rows/block
__global__ __launch_bounds__(256) void attn_kernel(
    const float* __restrict__ x,
    const unsigned short* __restrict__ qwb, const float* __restrict__ qb_s,
    const unsigned short* __restrict__ kbuf, const unsigned short* __restrict__ vp,
    const unsigned short* __restrict__ pwph, const unsigned short* __restrict__ pwpl,
    const float* __restrict__ proj_b,
    float* __restrict__ out)
{
    __shared__ char Ks[32768];   // K bf16 [256][64], XOR-swizzled rows
    __shared__ char Vs[32768];   // vp linear
    int bid = blockIdx.x;
    int b = bid >> 8, rt = bid & 255;
    int t = threadIdx.x;
    {
        const char* kb = (const char*)(kbuf + (size_t)b*16384);
        const char* vb = (const char*)(vp   + (size_t)b*16384);
        #pragma unroll
        for (int c = 0; c < 8; ++c) {
            int off = (c*256 + t) * 16;
            int dst = off ^ (((off >> 7) & 7) << 4);
            *(uint4*)(Ks + dst) = *(const uint4*)(kb + off);
            *(uint4*)(Vs + off) = *(const uint4*)(vb + off);
        }
    }
    __syncthreads();

    int w = t >> 6, lane = t & 63, g = lane >> 4, n = lane & 15;
    int qrow = rt*64 + w*16 + n;
    const float* xr = x + ((size_t)b*16384 + qrow) * 64;

    // ---- q-proj: qT[co][q] = sum_cin qwb[co][cin] * x[q][cin], +qb_s (scaled)
    f32x4 qacc[4];
    #pragma unroll
    for (int tau = 0; tau < 4; ++tau)
        qacc[tau] = *(const f32x4*)(qb_s + 16*tau + 4*g);
    bf16x8 xq[2];
    #pragma unroll
    for (int s = 0; s < 2; ++s) {
        float4 v0 = *(const float4*)(xr + 32*s + 8*g);
        float4 v1 = *(const float4*)(xr + 32*s + 8*g + 4);
        xq[s] = pack8(v0.x,v0.y,v0.z,v0.w,v1.x,v1.y,v1.z,v1.w);
    }
    #pragma unroll
    for (int tau = 0; tau < 4; ++tau)
        #pragma unroll
        for (int s = 0; s < 2; ++s) {
            bf16x8 A = ldg8(qwb + (16*tau + n)*64 + 32*s + 8*g);
            qacc[tau] = __builtin_amdgcn_mfma_f32_16x16x32_bf16(A, xq[s], qacc[tau], 0,0,0);
        }
    // pack Q^T B-frags: mu(g,i,s2) = 16*(2s2+(i>>2)) + 4g + (i&3) -> reg (tau,r)
    bf16x8 qkB[2];
    #pragma unroll
    for (int s2 = 0; s2 < 2; ++s2)
        qkB[s2] = pack8(qacc[2*s2][0],  qacc[2*s2][1],  qacc[2*s2][2],  qacc[2*s2][3],
                        qacc[2*s2+1][0],qacc[2*s2+1][1],qacc[2*s2+1][2],qacc[2*s2+1][3]);

    // ---- QK^T (swapped): S^T[m][q]; lane owns m = 16*tt + 4g + r for q = n
    float S[16][4];
    #pragma unroll
    for (int tt = 0; tt < 16; ++tt) {
        f32x4 sa = {0.f, 0.f, 0.f, 0.f};
        int m = 16*tt + n;
        int base = m * 128;
        int swz = (m & 7) << 4;
        #pragma unroll
        for (int s2 = 0; s2 < 2; ++s2) {
            int c1 = (32*s2 + 4*g) * 2;
            uint2 d0 = *(const uint2*)(Ks + ((base + c1)      ^ swz));
            uint2 d1 = *(const uint2*)(Ks + ((base + c1 + 32) ^ swz));
            U8 A; A.u = make_uint4(d0.x, d0.y, d1.x, d1.y);
            sa = __builtin_amdgcn_mfma_f32_16x16x32_bf16(A.v, qkB[s2], sa, 0,0,0);
        }
        S[tt][0]=sa[0]; S[tt][1]=sa[1]; S[tt][2]=sa[2]; S[tt][3]=sa[3];
    }

    // ---- softmax over m=256: lane-local tree + shfl_xor over 16,32
    float rm[16];
    #pragma unroll
    for (int tt = 0; tt < 16; ++tt)
        rm[tt] = fmaxf(fmaxf(S[tt][0],S[tt][1]), fmaxf(S[tt][2],S[tt][3]));
    float m8[8];
    #pragma unroll
    for (int j = 0; j < 8; ++j) m8[j] = fmaxf(rm[2*j], rm[2*j+1]);
    float mx = fmaxf(fmaxf(fmaxf(m8[0],m8[1]),fmaxf(m8[2],m8[3])),
                     fmaxf(fmaxf(m8[4],m8[5]),fmaxf(m8[6],m8[7])));
    mx = fmaxf(mx, __shfl_xor(mx, 16, 64));
    mx = fmaxf(mx, __shfl_xor(mx, 32, 64));
    #pragma unroll
    for (int tt = 0; tt < 16; ++tt)
        #pragma unroll
        for (int r = 0; r < 4; ++r)
            S[tt][r] = __expf(S[tt][r] - mx);
    float rs[16];
    #pragma unroll
    for (int tt = 0; tt < 16; ++tt) rs[tt] = (S[tt][0]+S[tt][1]) + (S[tt][2]+S[tt][3]);
    float s8[8];
    #pragma unroll
    for (int j = 0; j < 8; ++j) s8[j] = rs[2*j] + rs[2*j+1];
    float ssum = ((s8[0]+s8[1])+(s8[2]+s8[3])) + ((s8[4]+s8[5])+(s8[6]+s8[7]));
    ssum += __shfl_xor(ssum, 16, 64);
    ssum += __shfl_xor(ssum, 32, 64);
    float inv = 1.f / ssum;

    // ---- PV: out^T[ch][q] = sum_m V^T[ch][m] P^T[m][q]; P lane-local pack
    f32x4 oacc[4] = {{0,0,0,0},{0,0,0,0},{0,0,0,0},{0,0,0,0}};
    #pragma unroll
    for (int ks = 0; ks < 8; ++ks) {
        bf16x8 Bp = pack8(S[2*ks][0]*inv,  S[2*ks][1]*inv,  S[2*ks][2]*inv,  S[2*ks][3]*inv,
                          S[2*ks+1][0]*inv,S[2*ks+1][1]*inv,S[2*ks+1][2]*inv,S[2*ks+1][3]*inv);
        #pragma unroll
        for (int tc = 0; tc < 4; ++tc) {
            U8 A; A.u = *(const uint4*)(Vs + ((ks*4 + g)*64 + 16*tc + n) * 16);
            oacc[tc] = __builtin_amdgcn_mfma_f32_16x16x32_bf16(A.v, Bp, oacc[tc], 0,0,0);
        }
    }

    // ---- out-proj (split bf16 hi/lo): final^T[co][q] = pw x attnout^T + pb
    U8 BhU[2], BlU[2];
    #pragma unroll
    for (int s3 = 0; s3 < 2; ++s3) {
        unsigned short hb[8], lb[8];
        #pragma unroll
        for (int j = 0; j < 8; ++j) {
            float v = oacc[2*s3 + (j>>2)][j&3];
            hb[j] = f2bf(v);
            lb[j] = f2bf(v - bf2f(hb[j]));
        }
        BhU[s3].u.x = (unsigned)hb[0] | ((unsigned)hb[1]<<16);
        BhU[s3].u.y = (unsigned)hb[2] | ((unsigned)hb[3]<<16);
        BhU[s3].u.z = (unsigned)hb[4] | ((unsigned)hb[5]<<16);
        BhU[s3].u.w = (unsigned)hb[6] | ((unsigned)hb[7]<<16);
        BlU[s3].u.x = (unsigned)lb[0] | ((unsigned)lb[1]<<16);
        BlU[s3].u.y = (unsigned)lb[2] | ((unsigned)lb[3]<<16);
        BlU[s3].u.z = (unsigned)lb[4] | ((unsigned)lb[5]<<16);
        BlU[s3].u.w = (unsigned)lb[6] | ((unsigned)lb[7]<<16);
    }
    f32x4 pacc[4];
    #pragma unroll
    for (int tf = 0; tf < 4; ++tf)
        pacc[tf] = *(const f32x4*)(proj_b + 16*tf + 4*g);
    #pragma unroll
    for (int tf = 0; tf < 4; ++tf)
        #pragma unroll
        for (int s3 = 0; s3 < 2; ++s3) {
            bf16x8 Ah = ldg8(pwph + (((16*tf + n)*2 + s3)*4 + g)*8);
            bf16x8 Al = ldg8(pwpl + (((16*tf + n)*2 + s3)*4 + g)*8);
            pacc[tf] = __builtin_amdgcn_mfma_f32_16x16x32_bf16(Ah, BhU[s3].v, pacc[tf], 0,0,0);
            pacc[tf] = __builtin_amdgcn_mfma_f32_16x16x32_bf16(Ah, BlU[s3].v, pacc[tf], 0,0,0);
            pacc[tf] = __builtin_amdgcn_mfma_f32_16x16x32_bf16(Al, BhU[s3].v, pacc[tf], 0,0,0);
        }
    float* orow = out + ((size_t)b*16384 + qrow) * 64;
    #pragma unroll
    for (int tf = 0; tf < 4; ++tf)
        *(float4*)(orow + 16*tf + 4*g) = *(float4*)&pacc[tf];
}

extern "C" void kernel_launch(void* const* d_in, const int* in_sizes, int n_in,
                              void* d_out, int out_size, void* d_ws, size_t ws_size,
                              hipStream_t stream)
{
    const float* x      = (const float*)d_in[0];
    const float* sr_w   = (const float*)d_in[1];
    const float* sr_b   = (const float*)d_in[2];
    const float* ln_g   = (const float*)d_in[3];
    const float* ln_b   = (const float*)d_in[4];
    const float* q_w    = (const float*)d_in[5];
    const float* q_b    = (const float*)d_in[6];
    const float* kv_w   = (const float*)d_in[7];
    const float* kv_b   = (const float*)d_in[8];
    const float* proj_w = (const float*)d_in[9];
    const float* proj_b = (const float*)d_in[10];
    float* out = (float*)d_out;

    char* wsb = (char*)d_ws;
    unsigned short* wbp  = (unsigned short*)(wsb);            // 512KB
    float*          conv = (float*)(wsb + 524288);            // 512KB
    unsigned short* kbuf = (unsigned short*)(wsb + 1048576);  // 256KB
    unsigned short* vp   = (unsigned short*)(wsb + 1310720);  // 256KB
    unsigned short* qwb  = (unsigned short*)(wsb + 1572864);  // 8KB
    unsigned short* pwph = (unsigned short*)(wsb + 1581056);  // 8KB
    unsigned short* pwpl = (unsigned short*)(wsb + 1589248);  // 8KB
    float*          qb_s = (float*)(wsb + 1597440);           // 256B

    hipLaunchKernelGGL(prep_kernel, dim3(1024), dim3(256), 0, stream,
                       sr_w, sr_b, q_w, q_b, proj_w, wbp, conv, qwb, pwph, pwpl, qb_s);
    hipLaunchKernelGGL(conv_kernel, dim3(512), dim3(256), 0, stream, x, wbp, conv);
    hipLaunchKernelGGL(lnkv_kernel, dim3(2048), dim3(64), 0, stream,
                       conv, ln_g, ln_b, kv_w, kv_b, kbuf, vp);
    hipLaunchKernelGGL(attn_kernel, dim3(2048), dim3(256), 0, stream,
                       x, qwb, qb_s, kbuf, vp, pwph, pwpl, proj_b, out);
}